// Round 10
// baseline (114.515 us; speedup 1.0000x reference)
//
#include <hip/hip_runtime.h>

#define BATCH 8
#define NN 10000      // nodes per graph (N)
#define STB 1024      // 16 waves/CU; LDS: acc 80KB + table 40KB = 120KB

#define FPSCALE 4194304.0f          // 2^22 fixed-point scale
#define FPINV   2.384185791e-7f     // 1 / 2^22

typedef _Float16 h2 __attribute__((ext_vector_type(2)));

// Scatter via u32 fixed-point LDS atomics (bank-parallel path, isolated R8):
//  - gather table in LDS; pass 1 computes it from values (fused prep: tanh),
//    pass 2 copies the packed err2 table.
//  - acc[2][NN] int planes; q = rn(w * f * 2^22); ds_add_u32 is bank-parallel
//    (~18 cyc/wave-op) vs the serialized pk-f16 unit (222 cyc/wave-op, R7).
//  - range: |term| < 1.5M, degree <= ~350 -> |sum| < 0.5G << 2^31.
//  - epilogue: exact int sums -> h2 partials, int4-vectorized.
__global__ __launch_bounds__(STB, 1) void scatter_kernel(
        const float* __restrict__ vals,  // pass1: values (tanh staged); else null
        const h2* __restrict__ g2,       // pass2: err2 table [4*N]; else null
        const float* __restrict__ w,     // [E]
        const int* __restrict__ idx,     // [2,E]
        h2* __restrict__ partial,        // [K*4][N] h2
        int E, int N, int chunk, long goff, long soff)
{
    __shared__ __align__(16) int acc[2 * NN];        // 80KB
    __shared__ __align__(16) h2  table[NN];          // 40KB

    const int tid = threadIdx.x;
    const int k = blockIdx.x, bp = blockIdx.y;

    int4* az = (int4*)acc;
    for (int i = tid; i < 5000; i += STB) az[i] = make_int4(0, 0, 0, 0);
    if (vals) {
        // fused prep: table[i] = { tanh(v[2bp*N+i]), tanh(v[(2bp+1)*N+i]) }
        const float* va = vals + (long)(2 * bp) * N;
        const float* vb = va + N;
        for (int i = tid; i < N; i += STB) {
            h2 f = { (_Float16)tanhf(va[i]), (_Float16)tanhf(vb[i]) };
            table[i] = f;
        }
    } else {
        int4* tz = (int4*)table;
        const int4* gsrc = (const int4*)(g2 + (long)bp * N);
        for (int i = tid; i < 2500; i += STB) tz[i] = gsrc[i];
    }
    __syncthreads();

    long e0 = (long)k * chunk, e1 = e0 + chunk;
    if (e0 > E) e0 = E;
    if (e1 > E) e1 = E;
    long n = e1 - e0;
    long nv8 = n >> 3;                     // 8-edge groups
    const int4*   g4p = (const int4*)(idx + goff + e0);
    const int4*   s4p = (const int4*)(idx + soff + e0);
    const float4* w4p = (const float4*)(w + e0);

    for (long v = tid; v < nv8; v += STB) {
        int4 giA = g4p[2 * v], giB = g4p[2 * v + 1];
        int4 siA = s4p[2 * v], siB = s4p[2 * v + 1];
        float4 wvA = w4p[2 * v], wvB = w4p[2 * v + 1];
        int gi[8] = { giA.x, giA.y, giA.z, giA.w, giB.x, giB.y, giB.z, giB.w };
        int si[8] = { siA.x, siA.y, siA.z, siA.w, siB.x, siB.y, siB.z, siB.w };
        float wf[8] = { wvA.x, wvA.y, wvA.z, wvA.w, wvB.x, wvB.y, wvB.z, wvB.w };
        h2 f[8];
#pragma unroll
        for (int j = 0; j < 8; ++j) f[j] = table[gi[j]];   // 8 independent gathers
#pragma unroll
        for (int j = 0; j < 8; ++j) {
            float ws = wf[j] * FPSCALE;
            int q0 = __float2int_rn(ws * (float)f[j].x);
            int q1 = __float2int_rn(ws * (float)f[j].y);
            atomicAdd(&acc[si[j]], q0);          // ds_add_u32, plane 0
            atomicAdd(&acc[NN + si[j]], q1);     // ds_add_u32, plane 1
        }
    }
    for (long e = (nv8 << 3) + tid; e < n; e += STB) {
        int gi = idx[goff + e0 + e], si = idx[soff + e0 + e];
        float ws = w[e0 + e] * FPSCALE;
        h2 f = table[gi];
        atomicAdd(&acc[si],      __float2int_rn(ws * (float)f.x));
        atomicAdd(&acc[NN + si], __float2int_rn(ws * (float)f.y));
    }
    __syncthreads();

    // exact int sums -> h2 partial row (int4-vectorized: 4 nodes/iter)
    int4* pz = (int4*)(partial + ((long)k * 4 + bp) * N);
    const int4* p0 = (const int4*)acc;
    const int4* p1 = (const int4*)(acc + NN);
    for (int i = tid; i < 2500; i += STB) {
        int4 lo = p0[i], hi = p1[i];
        h2 o[4] = { { (_Float16)((float)lo.x * FPINV), (_Float16)((float)hi.x * FPINV) },
                    { (_Float16)((float)lo.y * FPINV), (_Float16)((float)hi.y * FPINV) },
                    { (_Float16)((float)lo.z * FPINV), (_Float16)((float)hi.z * FPINV) },
                    { (_Float16)((float)lo.w * FPINV), (_Float16)((float)hi.w * FPINV) } };
        pz[i] = *(int4*)o;
    }
}

// ---------------- reduce 1 (flat, 4 nodes/thread): pred, err, err2 ----------
__global__ __launch_bounds__(256) void reduce1_kernel(
        const h2* __restrict__ partial,
        const float* __restrict__ values,
        float* __restrict__ pred, float* __restrict__ err,
        h2* __restrict__ err2, int N, int K)
{
    int q = blockIdx.x * 256 + threadIdx.x;      // node-quad index
    int bp = blockIdx.y;
    int t = q * 4;
    if (t >= N) return;
    float se[4] = {0.f,0.f,0.f,0.f}, so[4] = {0.f,0.f,0.f,0.f};
    const char* pr = (const char*)(partial + (long)bp * N + t);
#pragma unroll 4
    for (int kk = 0; kk < K; ++kk) {
        int4 v = *(const int4*)(pr + (long)kk * 4 * N * sizeof(h2));
        h2* hp = (h2*)&v;
#pragma unroll
        for (int j = 0; j < 4; ++j) {
            se[j] += (float)hp[j].x; so[j] += (float)hp[j].y;
        }
    }
    long j0 = (long)(2 * bp) * N + t, j1 = j0 + N;
    float4 v0 = *(const float4*)(values + j0);
    float4 v1 = *(const float4*)(values + j1);
    float4 p0 = { se[0], se[1], se[2], se[3] };
    float4 p1 = { so[0], so[1], so[2], so[3] };
    float4 e0 = { v0.x - p0.x, v0.y - p0.y, v0.z - p0.z, v0.w - p0.w };
    float4 e1 = { v1.x - p1.x, v1.y - p1.y, v1.z - p1.z, v1.w - p1.w };
    *(float4*)(pred + j0) = p0;
    *(float4*)(pred + j1) = p1;
    *(float4*)(err + j0) = e0;
    *(float4*)(err + j1) = e1;
    h2 pk[4] = { { (_Float16)e0.x, (_Float16)e1.x },
                 { (_Float16)e0.y, (_Float16)e1.y },
                 { (_Float16)e0.z, (_Float16)e1.z },
                 { (_Float16)e0.w, (_Float16)e1.w } };
    *(int4*)(err2 + (long)bp * N + t) = *(int4*)pk;
}

// ---------------- reduce 2 (flat, 4 nodes/thread): dx ----------------
__global__ __launch_bounds__(256) void reduce2_kernel(
        const h2* __restrict__ partial,
        const float* __restrict__ values,
        const float* __restrict__ err,
        float* __restrict__ dx, int N, int K)
{
    int q = blockIdx.x * 256 + threadIdx.x;
    int bp = blockIdx.y;
    int t = q * 4;
    if (t >= N) return;
    float se[4] = {0.f,0.f,0.f,0.f}, so[4] = {0.f,0.f,0.f,0.f};
    const char* pr = (const char*)(partial + (long)bp * N + t);
#pragma unroll 4
    for (int kk = 0; kk < K; ++kk) {
        int4 v = *(const int4*)(pr + (long)kk * 4 * N * sizeof(h2));
        h2* hp = (h2*)&v;
#pragma unroll
        for (int j = 0; j < 4; ++j) {
            se[j] += (float)hp[j].x; so[j] += (float)hp[j].y;
        }
    }
    long j0 = (long)(2 * bp) * N + t, j1 = j0 + N;
    float4 v0 = *(const float4*)(values + j0);
    float4 v1 = *(const float4*)(values + j1);
    float4 e0 = *(const float4*)(err + j0);
    float4 e1 = *(const float4*)(err + j1);
    float4 d0, d1;
    float f;
    f = tanhf(v0.x); d0.x = e0.x - (1.0f - f * f) * se[0];
    f = tanhf(v0.y); d0.y = e0.y - (1.0f - f * f) * se[1];
    f = tanhf(v0.z); d0.z = e0.z - (1.0f - f * f) * se[2];
    f = tanhf(v0.w); d0.w = e0.w - (1.0f - f * f) * se[3];
    f = tanhf(v1.x); d1.x = e1.x - (1.0f - f * f) * so[0];
    f = tanhf(v1.y); d1.y = e1.y - (1.0f - f * f) * so[1];
    f = tanhf(v1.z); d1.z = e1.z - (1.0f - f * f) * so[2];
    f = tanhf(v1.w); d1.w = e1.w - (1.0f - f * f) * so[3];
    *(float4*)(dx + j0) = d0;
    *(float4*)(dx + j1) = d1;
}

extern "C" void kernel_launch(void* const* d_in, const int* in_sizes, int n_in,
                              void* d_out, int out_size, void* d_ws, size_t ws_size,
                              hipStream_t stream) {
    const float* values  = (const float*)d_in[0];   // [B*N]
    const float* weights = (const float*)d_in[1];   // [E]
    const int*   edge_ix = (const int*)d_in[2];     // [2, E]

    const int BN = in_sizes[0];        // 80000
    const int E  = in_sizes[1];        // 2,000,000
    const int N  = BN / BATCH;         // 10000

    float* out  = (float*)d_out;       // [3, B*N]
    float* pred = out;
    float* err  = out + BN;
    float* dx   = out + 2 * BN;

    // workspace: err2 [4N] h2 | partial [K*4][N] h2 (10.25MB)
    auto align16 = [](size_t x) { return (x + 15) & ~(size_t)15; };
    char* ws = (char*)d_ws;
    h2* err2 = (h2*)ws;
    size_t off = align16((size_t)4 * N * sizeof(h2));
    int K = 64;                        // 256 scatter blocks = 1/CU
    while (K > 16 && off + (size_t)K * 4 * N * sizeof(h2) > ws_size) K >>= 1;
    h2* partial = (h2*)(ws + off);

    int chunk = (((E + K - 1) / K) + 7) & ~7;   // multiple of 8
    int Kused = (E + chunk - 1) / chunk;

    dim3 sgrid(Kused, 4);                     // 4 batch-pairs
    dim3 rgrid((N / 4 + 255) / 256, 4);       // 4 nodes per thread

    // pass 1: table = tanh(values) staged in-block; gather src, scatter tgt
    scatter_kernel<<<sgrid, STB, 0, stream>>>(values, nullptr, weights, edge_ix,
                                              partial, E, N, chunk, 0L, (long)E);
    reduce1_kernel<<<rgrid, 256, 0, stream>>>(partial, values, pred, err,
                                              err2, N, Kused);
    // pass 2: table = err2; gather tgt, scatter src
    scatter_kernel<<<sgrid, STB, 0, stream>>>(nullptr, err2, weights, edge_ix,
                                              partial, E, N, chunk, (long)E, 0L);
    reduce2_kernel<<<rgrid, 256, 0, stream>>>(partial, values, err, dx,
                                              N, Kused);
}

// Round 12
// 107.685 us; speedup vs baseline: 1.0634x; 1.0634x over previous
//
#include <hip/hip_runtime.h>

#define BATCH 8
#define NN 10000      // nodes per graph (N)
#define STB 1024      // 16 waves/CU; LDS: acc 80KB + table 40KB = 120KB

#define FPSCALE 4194304.0f          // 2^22 fixed-point scale
#define FPINV   2.384185791e-7f     // 1 / 2^22

typedef _Float16 h2 __attribute__((ext_vector_type(2)));

// Scatter via u32 fixed-point LDS atomics (bank-parallel path, isolated R8):
//  - gather table in LDS; pass 1 computes it from values (fused prep: tanh),
//    pass 2 copies the packed err2 table.
//  - acc[2][NN] int planes; q = rn(w * f * 2^22); ds_add_u32 is bank-parallel
//    (~18 cyc/wave-op) vs the serialized pk-f16 unit (222 cyc/wave-op, R7).
//  - range: |term| < 1.5M, degree <= ~350 -> |sum| < 0.5G << 2^31.
//  - epilogue: exact int sums -> h2 partials, int4-vectorized.
// NOTE (R11): hipLaunchCooperativeKernel inside this harness's graph capture
// hangs the container -- do NOT reintroduce it. Plain 4-dispatch only.
__global__ __launch_bounds__(STB, 1) void scatter_kernel(
        const float* __restrict__ vals,  // pass1: values (tanh staged); else null
        const h2* __restrict__ g2,       // pass2: err2 table [4*N]; else null
        const float* __restrict__ w,     // [E]
        const int* __restrict__ idx,     // [2,E]
        h2* __restrict__ partial,        // [K*4][N] h2
        int E, int N, int chunk, long goff, long soff)
{
    __shared__ __align__(16) int acc[2 * NN];        // 80KB
    __shared__ __align__(16) h2  table[NN];          // 40KB

    const int tid = threadIdx.x;
    const int k = blockIdx.x, bp = blockIdx.y;

    int4* az = (int4*)acc;
    for (int i = tid; i < 5000; i += STB) az[i] = make_int4(0, 0, 0, 0);
    if (vals) {
        // fused prep: table[i] = { tanh(v[2bp*N+i]), tanh(v[(2bp+1)*N+i]) }
        const float* va = vals + (long)(2 * bp) * N;
        const float* vb = va + N;
        for (int i = tid; i < N; i += STB) {
            h2 f = { (_Float16)tanhf(va[i]), (_Float16)tanhf(vb[i]) };
            table[i] = f;
        }
    } else {
        int4* tz = (int4*)table;
        const int4* gsrc = (const int4*)(g2 + (long)bp * N);
        for (int i = tid; i < 2500; i += STB) tz[i] = gsrc[i];
    }
    __syncthreads();

    long e0 = (long)k * chunk, e1 = e0 + chunk;
    if (e0 > E) e0 = E;
    if (e1 > E) e1 = E;
    long n = e1 - e0;
    long nv8 = n >> 3;                     // 8-edge groups
    const int4*   g4p = (const int4*)(idx + goff + e0);
    const int4*   s4p = (const int4*)(idx + soff + e0);
    const float4* w4p = (const float4*)(w + e0);

    for (long v = tid; v < nv8; v += STB) {
        int4 giA = g4p[2 * v], giB = g4p[2 * v + 1];
        int4 siA = s4p[2 * v], siB = s4p[2 * v + 1];
        float4 wvA = w4p[2 * v], wvB = w4p[2 * v + 1];
        int gi[8] = { giA.x, giA.y, giA.z, giA.w, giB.x, giB.y, giB.z, giB.w };
        int si[8] = { siA.x, siA.y, siA.z, siA.w, siB.x, siB.y, siB.z, siB.w };
        float wf[8] = { wvA.x, wvA.y, wvA.z, wvA.w, wvB.x, wvB.y, wvB.z, wvB.w };
        h2 f[8];
#pragma unroll
        for (int j = 0; j < 8; ++j) f[j] = table[gi[j]];   // 8 independent gathers
#pragma unroll
        for (int j = 0; j < 8; ++j) {
            float ws = wf[j] * FPSCALE;
            int q0 = __float2int_rn(ws * (float)f[j].x);
            int q1 = __float2int_rn(ws * (float)f[j].y);
            atomicAdd(&acc[si[j]], q0);          // ds_add_u32, plane 0
            atomicAdd(&acc[NN + si[j]], q1);     // ds_add_u32, plane 1
        }
    }
    for (long e = (nv8 << 3) + tid; e < n; e += STB) {
        int gi = idx[goff + e0 + e], si = idx[soff + e0 + e];
        float ws = w[e0 + e] * FPSCALE;
        h2 f = table[gi];
        atomicAdd(&acc[si],      __float2int_rn(ws * (float)f.x));
        atomicAdd(&acc[NN + si], __float2int_rn(ws * (float)f.y));
    }
    __syncthreads();

    // exact int sums -> h2 partial row (int4-vectorized: 4 nodes/iter)
    int4* pz = (int4*)(partial + ((long)k * 4 + bp) * N);
    const int4* p0 = (const int4*)acc;
    const int4* p1 = (const int4*)(acc + NN);
    for (int i = tid; i < 2500; i += STB) {
        int4 lo = p0[i], hi = p1[i];
        h2 o[4] = { { (_Float16)((float)lo.x * FPINV), (_Float16)((float)hi.x * FPINV) },
                    { (_Float16)((float)lo.y * FPINV), (_Float16)((float)hi.y * FPINV) },
                    { (_Float16)((float)lo.z * FPINV), (_Float16)((float)hi.z * FPINV) },
                    { (_Float16)((float)lo.w * FPINV), (_Float16)((float)hi.w * FPINV) } };
        pz[i] = *(int4*)o;
    }
}

// ---------------- reduce 1 (flat, 1 node/thread -- R9 proven): -------------
// pred, err, err2. 160x4 blocks, coalesced strided h2 loads, f32 accumulate.
__global__ __launch_bounds__(256) void reduce1_kernel(
        const h2* __restrict__ partial,
        const float* __restrict__ values,
        float* __restrict__ pred, float* __restrict__ err,
        h2* __restrict__ err2, int N, int K)
{
    int t = blockIdx.x * 256 + threadIdx.x;
    int bp = blockIdx.y;
    if (t >= N) return;
    float sx = 0.f, sy = 0.f;
    const h2* __restrict__ p = partial + (long)bp * N + t;
#pragma unroll 8
    for (int kk = 0; kk < K; ++kk) {
        h2 v = p[(long)kk * 4 * N];
        sx += (float)v.x; sy += (float)v.y;
    }
    long j0 = (long)(2 * bp) * N + t, j1 = j0 + N;
    float v0 = values[j0], v1 = values[j1];
    float e0 = v0 - sx, e1 = v1 - sy;
    pred[j0] = sx; pred[j1] = sy;
    err[j0] = e0;  err[j1] = e1;
    h2 pk = { (_Float16)e0, (_Float16)e1 };
    err2[(long)bp * N + t] = pk;
}

// ---------------- reduce 2 (flat, 1 node/thread): dx ----------------
__global__ __launch_bounds__(256) void reduce2_kernel(
        const h2* __restrict__ partial,
        const float* __restrict__ values,
        const float* __restrict__ err,
        float* __restrict__ dx, int N, int K)
{
    int t = blockIdx.x * 256 + threadIdx.x;
    int bp = blockIdx.y;
    if (t >= N) return;
    float sx = 0.f, sy = 0.f;
    const h2* __restrict__ p = partial + (long)bp * N + t;
#pragma unroll 8
    for (int kk = 0; kk < K; ++kk) {
        h2 v = p[(long)kk * 4 * N];
        sx += (float)v.x; sy += (float)v.y;
    }
    long j0 = (long)(2 * bp) * N + t, j1 = j0 + N;
    float v0 = values[j0], v1 = values[j1];
    float f0 = tanhf(v0), f1 = tanhf(v1);
    dx[j0] = err[j0] - (1.0f - f0 * f0) * sx;
    dx[j1] = err[j1] - (1.0f - f1 * f1) * sy;
}

extern "C" void kernel_launch(void* const* d_in, const int* in_sizes, int n_in,
                              void* d_out, int out_size, void* d_ws, size_t ws_size,
                              hipStream_t stream) {
    const float* values  = (const float*)d_in[0];   // [B*N]
    const float* weights = (const float*)d_in[1];   // [E]
    const int*   edge_ix = (const int*)d_in[2];     // [2, E]

    const int BN = in_sizes[0];        // 80000
    const int E  = in_sizes[1];        // 2,000,000
    const int N  = BN / BATCH;         // 10000

    float* out  = (float*)d_out;       // [3, B*N]
    float* pred = out;
    float* err  = out + BN;
    float* dx   = out + 2 * BN;

    // workspace: err2 [4N] h2 | partial [K*4][N] h2 (10.25MB @ K=64)
    auto align16 = [](size_t x) { return (x + 15) & ~(size_t)15; };
    char* ws = (char*)d_ws;
    h2* err2 = (h2*)ws;
    size_t off = align16((size_t)4 * N * sizeof(h2));
    int K = 64;                        // 256 scatter blocks = 1/CU
    while (K > 16 && off + (size_t)K * 4 * N * sizeof(h2) > ws_size) K >>= 1;
    h2* partial = (h2*)(ws + off);

    int chunk = (((E + K - 1) / K) + 7) & ~7;   // multiple of 8
    int Kused = (E + chunk - 1) / chunk;

    dim3 sgrid(Kused, 4);                 // 4 batch-pairs
    dim3 rgrid((N + 255) / 256, 4);       // 1 node per thread (R9 proven)

    // pass 1: table = tanh(values) staged in-block; gather src, scatter tgt
    scatter_kernel<<<sgrid, STB, 0, stream>>>(values, nullptr, weights, edge_ix,
                                              partial, E, N, chunk, 0L, (long)E);
    reduce1_kernel<<<rgrid, 256, 0, stream>>>(partial, values, pred, err,
                                              err2, N, Kused);
    // pass 2: table = err2; gather tgt, scatter src
    scatter_kernel<<<sgrid, STB, 0, stream>>>(nullptr, err2, weights, edge_ix,
                                              partial, E, N, chunk, (long)E, 0L);
    reduce2_kernel<<<rgrid, 256, 0, stream>>>(partial, values, err, dx,
                                              N, Kused);
}

// Round 13
// 103.846 us; speedup vs baseline: 1.1027x; 1.0370x over previous
//
#include <hip/hip_runtime.h>

#define BATCH 8
#define NN 10000      // nodes per graph (N)
#define STB 1024      // 16 waves/CU; LDS: acc64 80KB + table 40KB = 120KB

#define FPSCALE 4194304.0f          // 2^22 fixed-point scale
#define FPINV   2.384185791e-7f     // 1 / 2^22

typedef _Float16 h2 __attribute__((ext_vector_type(2)));

// decode packed 64-bit accumulator: S = (Sum q1)<<32 + (Sum q0), exact while
// |Sum q0| < 2^31 (bound: deg<=~350, |term|<1.5M -> |sum|<0.5G). Borrows from
// negative q0 terms propagate into the high half and cancel in the decode.
__device__ __forceinline__ h2 dec64(long long S) {
    int q0 = (int)(unsigned)(S & 0xffffffffll);
    long long rest = S - (long long)q0;
    int q1 = (int)(rest >> 32);
    h2 r = { (_Float16)((float)q0 * FPINV), (_Float16)((float)q1 * FPINV) };
    return r;
}

// Scatter via ONE u64 fixed-point LDS atomic per edge (ds_add_u64):
//  - R8 isolated: integer DS atomics are bank-parallel; the pk-f16 unit is
//    serialized (3.5cyc/lane, occupancy-invariant). R12 budget: the 976
//    ds_add_u32 wave-ops dominate scatter (~10 of ~16us). Packing both batch
//    planes into one 64-bit atomic halves the op count (976 -> 488).
//  - gather table in LDS; pass 1 computes it from values (fused tanh prep),
//    pass 2 copies the packed err2 table.
// NOTE (R11): hipLaunchCooperativeKernel inside this harness's graph capture
// hangs the container -- do NOT reintroduce it. Plain 4-dispatch only.
__global__ __launch_bounds__(STB, 1) void scatter_kernel(
        const float* __restrict__ vals,  // pass1: values (tanh staged); else null
        const h2* __restrict__ g2,       // pass2: err2 table [4*N]; else null
        const float* __restrict__ w,     // [E]
        const int* __restrict__ idx,     // [2,E]
        h2* __restrict__ partial,        // [K*4][N] h2
        int E, int N, int chunk, long goff, long soff)
{
    __shared__ __align__(16) unsigned long long acc64[NN];   // 80KB
    __shared__ __align__(16) h2 table[NN];                   // 40KB

    const int tid = threadIdx.x;
    const int k = blockIdx.x, bp = blockIdx.y;

    int4* az = (int4*)acc64;
    for (int i = tid; i < 5000; i += STB) az[i] = make_int4(0, 0, 0, 0);
    if (vals) {
        // fused prep: table[i] = { tanh(v[2bp*N+i]), tanh(v[(2bp+1)*N+i]) }
        const float4* va = (const float4*)(vals + (long)(2 * bp) * N);
        const float4* vb = (const float4*)(vals + (long)(2 * bp + 1) * N);
        for (int i = tid; i < 2500; i += STB) {       // 4 nodes/iter
            float4 a = va[i], b = vb[i];
            h2 o[4] = { { (_Float16)tanhf(a.x), (_Float16)tanhf(b.x) },
                        { (_Float16)tanhf(a.y), (_Float16)tanhf(b.y) },
                        { (_Float16)tanhf(a.z), (_Float16)tanhf(b.z) },
                        { (_Float16)tanhf(a.w), (_Float16)tanhf(b.w) } };
            *(int4*)&table[i * 4] = *(int4*)o;
        }
    } else {
        int4* tz = (int4*)table;
        const int4* gsrc = (const int4*)(g2 + (long)bp * N);
        for (int i = tid; i < 2500; i += STB) tz[i] = gsrc[i];
    }
    __syncthreads();

    long e0 = (long)k * chunk, e1 = e0 + chunk;
    if (e0 > E) e0 = E;
    if (e1 > E) e1 = E;
    long n = e1 - e0;
    long nv8 = n >> 3;                     // 8-edge groups
    const int4*   g4p = (const int4*)(idx + goff + e0);
    const int4*   s4p = (const int4*)(idx + soff + e0);
    const float4* w4p = (const float4*)(w + e0);

    for (long v = tid; v < nv8; v += STB) {
        int4 giA = g4p[2 * v], giB = g4p[2 * v + 1];
        int4 siA = s4p[2 * v], siB = s4p[2 * v + 1];
        float4 wvA = w4p[2 * v], wvB = w4p[2 * v + 1];
        int gi[8] = { giA.x, giA.y, giA.z, giA.w, giB.x, giB.y, giB.z, giB.w };
        int si[8] = { siA.x, siA.y, siA.z, siA.w, siB.x, siB.y, siB.z, siB.w };
        float wf[8] = { wvA.x, wvA.y, wvA.z, wvA.w, wvB.x, wvB.y, wvB.z, wvB.w };
        h2 f[8];
#pragma unroll
        for (int j = 0; j < 8; ++j) f[j] = table[gi[j]];   // 8 independent gathers
#pragma unroll
        for (int j = 0; j < 8; ++j) {
            float ws = wf[j] * FPSCALE;
            long long q0 = (long long)__float2int_rn(ws * (float)f[j].x);
            long long q1 = (long long)__float2int_rn(ws * (float)f[j].y);
            unsigned long long t = (unsigned long long)((q1 << 32) + q0);
            atomicAdd(&acc64[si[j]], t);         // ONE ds_add_u64 per edge
        }
    }
    for (long e = (nv8 << 3) + tid; e < n; e += STB) {
        int gi = idx[goff + e0 + e], si = idx[soff + e0 + e];
        float ws = w[e0 + e] * FPSCALE;
        h2 f = table[gi];
        long long q0 = (long long)__float2int_rn(ws * (float)f.x);
        long long q1 = (long long)__float2int_rn(ws * (float)f.y);
        atomicAdd(&acc64[si], (unsigned long long)((q1 << 32) + q0));
    }
    __syncthreads();

    // decode exact packed sums -> h2 partial row (4 nodes/iter)
    int4* pz = (int4*)(partial + ((long)k * 4 + bp) * N);
    const longlong2* a2 = (const longlong2*)acc64;
    for (int i = tid; i < 2500; i += STB) {
        longlong2 u = a2[2 * i], v = a2[2 * i + 1];
        h2 o[4] = { dec64(u.x), dec64(u.y), dec64(v.x), dec64(v.y) };
        pz[i] = *(int4*)o;
    }
}

// ---------------- reduce 1 (flat, 1 node/thread -- R9 proven): -------------
__global__ __launch_bounds__(256) void reduce1_kernel(
        const h2* __restrict__ partial,
        const float* __restrict__ values,
        float* __restrict__ pred, float* __restrict__ err,
        h2* __restrict__ err2, int N, int K)
{
    int t = blockIdx.x * 256 + threadIdx.x;
    int bp = blockIdx.y;
    if (t >= N) return;
    float sx = 0.f, sy = 0.f;
    const h2* __restrict__ p = partial + (long)bp * N + t;
#pragma unroll 8
    for (int kk = 0; kk < K; ++kk) {
        h2 v = p[(long)kk * 4 * N];
        sx += (float)v.x; sy += (float)v.y;
    }
    long j0 = (long)(2 * bp) * N + t, j1 = j0 + N;
    float v0 = values[j0], v1 = values[j1];
    float e0 = v0 - sx, e1 = v1 - sy;
    pred[j0] = sx; pred[j1] = sy;
    err[j0] = e0;  err[j1] = e1;
    h2 pk = { (_Float16)e0, (_Float16)e1 };
    err2[(long)bp * N + t] = pk;
}

// ---------------- reduce 2 (flat, 1 node/thread): dx ----------------
__global__ __launch_bounds__(256) void reduce2_kernel(
        const h2* __restrict__ partial,
        const float* __restrict__ values,
        const float* __restrict__ err,
        float* __restrict__ dx, int N, int K)
{
    int t = blockIdx.x * 256 + threadIdx.x;
    int bp = blockIdx.y;
    if (t >= N) return;
    float sx = 0.f, sy = 0.f;
    const h2* __restrict__ p = partial + (long)bp * N + t;
#pragma unroll 8
    for (int kk = 0; kk < K; ++kk) {
        h2 v = p[(long)kk * 4 * N];
        sx += (float)v.x; sy += (float)v.y;
    }
    long j0 = (long)(2 * bp) * N + t, j1 = j0 + N;
    float v0 = values[j0], v1 = values[j1];
    float f0 = tanhf(v0), f1 = tanhf(v1);
    dx[j0] = err[j0] - (1.0f - f0 * f0) * sx;
    dx[j1] = err[j1] - (1.0f - f1 * f1) * sy;
}

extern "C" void kernel_launch(void* const* d_in, const int* in_sizes, int n_in,
                              void* d_out, int out_size, void* d_ws, size_t ws_size,
                              hipStream_t stream) {
    const float* values  = (const float*)d_in[0];   // [B*N]
    const float* weights = (const float*)d_in[1];   // [E]
    const int*   edge_ix = (const int*)d_in[2];     // [2, E]

    const int BN = in_sizes[0];        // 80000
    const int E  = in_sizes[1];        // 2,000,000
    const int N  = BN / BATCH;         // 10000

    float* out  = (float*)d_out;       // [3, B*N]
    float* pred = out;
    float* err  = out + BN;
    float* dx   = out + 2 * BN;

    // workspace: err2 [4N] h2 | partial [K*4][N] h2 (10.25MB @ K=64)
    auto align16 = [](size_t x) { return (x + 15) & ~(size_t)15; };
    char* ws = (char*)d_ws;
    h2* err2 = (h2*)ws;
    size_t off = align16((size_t)4 * N * sizeof(h2));
    int K = 64;                        // 256 scatter blocks = 1/CU
    while (K > 16 && off + (size_t)K * 4 * N * sizeof(h2) > ws_size) K >>= 1;
    h2* partial = (h2*)(ws + off);

    int chunk = (((E + K - 1) / K) + 7) & ~7;   // multiple of 8
    int Kused = (E + chunk - 1) / chunk;

    dim3 sgrid(Kused, 4);                 // 4 batch-pairs
    dim3 rgrid((N + 255) / 256, 4);       // 1 node per thread (R9 proven)

    // pass 1: table = tanh(values) staged in-block; gather src, scatter tgt
    scatter_kernel<<<sgrid, STB, 0, stream>>>(values, nullptr, weights, edge_ix,
                                              partial, E, N, chunk, 0L, (long)E);
    reduce1_kernel<<<rgrid, 256, 0, stream>>>(partial, values, pred, err,
                                              err2, N, Kused);
    // pass 2: table = err2; gather tgt, scatter src
    scatter_kernel<<<sgrid, STB, 0, stream>>>(nullptr, err2, weights, edge_ix,
                                              partial, E, N, chunk, (long)E, 0L);
    reduce2_kernel<<<rgrid, 256, 0, stream>>>(partial, values, err, dx,
                                              N, Kused);
}

// Round 14
// 100.715 us; speedup vs baseline: 1.1370x; 1.0311x over previous
//
#include <hip/hip_runtime.h>

#define BATCH 8
#define NN 10000      // nodes per graph (N)
#define STB 1024      // 16 waves/CU; LDS: acc64 80KB + table 40KB = 120KB

#define FPSCALE 4194304.0f          // 2^22 fixed-point scale
#define FPINV   2.384185791e-7f     // 1 / 2^22

typedef _Float16 h2 __attribute__((ext_vector_type(2)));

// decode packed 64-bit accumulator: S = (Sum q1)<<32 + (Sum q0), exact while
// |Sum q0| < 2^31 (bound: deg<=~350, |term|<1.5M -> |sum|<0.5G). Borrows from
// negative q0 terms propagate into the high half and cancel in the decode.
__device__ __forceinline__ h2 dec64(long long S) {
    int q0 = (int)(unsigned)(S & 0xffffffffll);
    long long rest = S - (long long)q0;
    int q1 = (int)(rest >> 32);
    h2 r = { (_Float16)((float)q0 * FPINV), (_Float16)((float)q1 * FPINV) };
    return r;
}

// Scatter via ONE u64 fixed-point LDS atomic per edge (ds_add_u64):
//  - R8 isolated: integer DS atomics are bank-parallel; the pk-f16 unit is
//    serialized (3.5cyc/lane, occupancy-invariant). R13: u64 packing (488
//    atomic wave-ops) = 103.8us total, ~4us better than 2x u32.
//  - gather table in LDS; pass 1 computes it from values (fused tanh prep),
//    pass 2 copies the packed err2 table.
// NOTE (R11): hipLaunchCooperativeKernel inside this harness's graph capture
// hangs the container -- do NOT reintroduce it. Plain 4-dispatch only.
__global__ __launch_bounds__(STB, 1) void scatter_kernel(
        const float* __restrict__ vals,  // pass1: values (tanh staged); else null
        const h2* __restrict__ g2,       // pass2: err2 table [4*N]; else null
        const float* __restrict__ w,     // [E]
        const int* __restrict__ idx,     // [2,E]
        h2* __restrict__ partial,        // [K*4][N] h2
        int E, int N, int chunk, long goff, long soff)
{
    __shared__ __align__(16) unsigned long long acc64[NN];   // 80KB
    __shared__ __align__(16) h2 table[NN];                   // 40KB

    const int tid = threadIdx.x;
    const int k = blockIdx.x, bp = blockIdx.y;

    int4* az = (int4*)acc64;
    for (int i = tid; i < 5000; i += STB) az[i] = make_int4(0, 0, 0, 0);
    if (vals) {
        // fused prep: table[i] = { tanh(v[2bp*N+i]), tanh(v[(2bp+1)*N+i]) }
        const float4* va = (const float4*)(vals + (long)(2 * bp) * N);
        const float4* vb = (const float4*)(vals + (long)(2 * bp + 1) * N);
        for (int i = tid; i < 2500; i += STB) {       // 4 nodes/iter
            float4 a = va[i], b = vb[i];
            h2 o[4] = { { (_Float16)tanhf(a.x), (_Float16)tanhf(b.x) },
                        { (_Float16)tanhf(a.y), (_Float16)tanhf(b.y) },
                        { (_Float16)tanhf(a.z), (_Float16)tanhf(b.z) },
                        { (_Float16)tanhf(a.w), (_Float16)tanhf(b.w) } };
            *(int4*)&table[i * 4] = *(int4*)o;
        }
    } else {
        int4* tz = (int4*)table;
        const int4* gsrc = (const int4*)(g2 + (long)bp * N);
        for (int i = tid; i < 2500; i += STB) tz[i] = gsrc[i];
    }
    __syncthreads();

    long e0 = (long)k * chunk, e1 = e0 + chunk;
    if (e0 > E) e0 = E;
    if (e1 > E) e1 = E;
    long n = e1 - e0;
    long nv8 = n >> 3;                     // 8-edge groups
    const int4*   g4p = (const int4*)(idx + goff + e0);
    const int4*   s4p = (const int4*)(idx + soff + e0);
    const float4* w4p = (const float4*)(w + e0);

    for (long v = tid; v < nv8; v += STB) {
        int4 giA = g4p[2 * v], giB = g4p[2 * v + 1];
        int4 siA = s4p[2 * v], siB = s4p[2 * v + 1];
        float4 wvA = w4p[2 * v], wvB = w4p[2 * v + 1];
        int gi[8] = { giA.x, giA.y, giA.z, giA.w, giB.x, giB.y, giB.z, giB.w };
        int si[8] = { siA.x, siA.y, siA.z, siA.w, siB.x, siB.y, siB.z, siB.w };
        float wf[8] = { wvA.x, wvA.y, wvA.z, wvA.w, wvB.x, wvB.y, wvB.z, wvB.w };
        h2 f[8];
#pragma unroll
        for (int j = 0; j < 8; ++j) f[j] = table[gi[j]];   // 8 independent gathers
#pragma unroll
        for (int j = 0; j < 8; ++j) {
            float ws = wf[j] * FPSCALE;
            long long q0 = (long long)__float2int_rn(ws * (float)f[j].x);
            long long q1 = (long long)__float2int_rn(ws * (float)f[j].y);
            unsigned long long t = (unsigned long long)((q1 << 32) + q0);
            atomicAdd(&acc64[si[j]], t);         // ONE ds_add_u64 per edge
        }
    }
    for (long e = (nv8 << 3) + tid; e < n; e += STB) {
        int gi = idx[goff + e0 + e], si = idx[soff + e0 + e];
        float ws = w[e0 + e] * FPSCALE;
        h2 f = table[gi];
        long long q0 = (long long)__float2int_rn(ws * (float)f.x);
        long long q1 = (long long)__float2int_rn(ws * (float)f.y);
        atomicAdd(&acc64[si], (unsigned long long)((q1 << 32) + q0));
    }
    __syncthreads();

    // decode exact packed sums -> h2 partial row (4 nodes/iter)
    int4* pz = (int4*)(partial + ((long)k * 4 + bp) * N);
    const longlong2* a2 = (const longlong2*)acc64;
    for (int i = tid; i < 2500; i += STB) {
        longlong2 u = a2[2 * i], v = a2[2 * i + 1];
        h2 o[4] = { dec64(u.x), dec64(u.y), dec64(v.x), dec64(v.y) };
        pz[i] = *(int4*)o;
    }
}

// ---------------- reduce 1: pred, err, err2 (4 threads/node, k-split) -------
// R13 budget put the reduces at ~5us each: 41k threads = 640 waves chip-wide,
// latency-bound on 64 strided loads. 4-way k-split -> 164k threads (2560
// waves, 10/CU), 16 loads/thread; each wave = one k-quarter x 64 adjacent
// nodes (coalesced 256B loads); LDS combine.
__global__ __launch_bounds__(256) void reduce1_kernel(
        const h2* __restrict__ partial,
        const float* __restrict__ values,
        float* __restrict__ pred, float* __restrict__ err,
        h2* __restrict__ err2, int N, int K)
{
    __shared__ float2 sm[256];
    const int nl = threadIdx.x & 63;        // node within tile
    const int q  = threadIdx.x >> 6;        // k-quarter (= wave id)
    const int bp = blockIdx.y;
    const int t  = blockIdx.x * 64 + nl;
    float sx = 0.f, sy = 0.f;
    if (t < N) {
        const h2* __restrict__ p = partial + (long)bp * N + t;
#pragma unroll 4
        for (int kk = q; kk < K; kk += 4) {
            h2 v = p[(long)kk * 4 * N];
            sx += (float)v.x; sy += (float)v.y;
        }
    }
    sm[threadIdx.x] = make_float2(sx, sy);
    __syncthreads();
    if (q == 0 && t < N) {
        float2 s1 = sm[nl + 64], s2 = sm[nl + 128], s3 = sm[nl + 192];
        sx += s1.x + s2.x + s3.x;
        sy += s1.y + s2.y + s3.y;
        long j0 = (long)(2 * bp) * N + t, j1 = j0 + N;
        float v0 = values[j0], v1 = values[j1];
        float e0 = v0 - sx, e1 = v1 - sy;
        pred[j0] = sx; pred[j1] = sy;
        err[j0] = e0;  err[j1] = e1;
        h2 pk = { (_Float16)e0, (_Float16)e1 };
        err2[(long)bp * N + t] = pk;
    }
}

// ---------------- reduce 2: dx (4 threads/node, k-split) ----------------
__global__ __launch_bounds__(256) void reduce2_kernel(
        const h2* __restrict__ partial,
        const float* __restrict__ values,
        const float* __restrict__ err,
        float* __restrict__ dx, int N, int K)
{
    __shared__ float2 sm[256];
    const int nl = threadIdx.x & 63;
    const int q  = threadIdx.x >> 6;
    const int bp = blockIdx.y;
    const int t  = blockIdx.x * 64 + nl;
    float sx = 0.f, sy = 0.f;
    if (t < N) {
        const h2* __restrict__ p = partial + (long)bp * N + t;
#pragma unroll 4
        for (int kk = q; kk < K; kk += 4) {
            h2 v = p[(long)kk * 4 * N];
            sx += (float)v.x; sy += (float)v.y;
        }
    }
    sm[threadIdx.x] = make_float2(sx, sy);
    __syncthreads();
    if (q == 0 && t < N) {
        float2 s1 = sm[nl + 64], s2 = sm[nl + 128], s3 = sm[nl + 192];
        sx += s1.x + s2.x + s3.x;
        sy += s1.y + s2.y + s3.y;
        long j0 = (long)(2 * bp) * N + t, j1 = j0 + N;
        float v0 = values[j0], v1 = values[j1];
        float f0 = tanhf(v0), f1 = tanhf(v1);
        dx[j0] = err[j0] - (1.0f - f0 * f0) * sx;
        dx[j1] = err[j1] - (1.0f - f1 * f1) * sy;
    }
}

extern "C" void kernel_launch(void* const* d_in, const int* in_sizes, int n_in,
                              void* d_out, int out_size, void* d_ws, size_t ws_size,
                              hipStream_t stream) {
    const float* values  = (const float*)d_in[0];   // [B*N]
    const float* weights = (const float*)d_in[1];   // [E]
    const int*   edge_ix = (const int*)d_in[2];     // [2, E]

    const int BN = in_sizes[0];        // 80000
    const int E  = in_sizes[1];        // 2,000,000
    const int N  = BN / BATCH;         // 10000

    float* out  = (float*)d_out;       // [3, B*N]
    float* pred = out;
    float* err  = out + BN;
    float* dx   = out + 2 * BN;

    // workspace: err2 [4N] h2 | partial [K*4][N] h2 (10.25MB @ K=64)
    auto align16 = [](size_t x) { return (x + 15) & ~(size_t)15; };
    char* ws = (char*)d_ws;
    h2* err2 = (h2*)ws;
    size_t off = align16((size_t)4 * N * sizeof(h2));
    int K = 64;                        // 256 scatter blocks = 1/CU
    while (K > 16 && off + (size_t)K * 4 * N * sizeof(h2) > ws_size) K >>= 1;
    h2* partial = (h2*)(ws + off);

    int chunk = (((E + K - 1) / K) + 7) & ~7;   // multiple of 8
    int Kused = (E + chunk - 1) / chunk;

    dim3 sgrid(Kused, 4);                 // 4 batch-pairs
    dim3 rgrid((N + 63) / 64, 4);         // 628 blocks, 4 threads/node

    // pass 1: table = tanh(values) staged in-block; gather src, scatter tgt
    scatter_kernel<<<sgrid, STB, 0, stream>>>(values, nullptr, weights, edge_ix,
                                              partial, E, N, chunk, 0L, (long)E);
    reduce1_kernel<<<rgrid, 256, 0, stream>>>(partial, values, pred, err,
                                              err2, N, Kused);
    // pass 2: table = err2; gather tgt, scatter src
    scatter_kernel<<<sgrid, STB, 0, stream>>>(nullptr, err2, weights, edge_ix,
                                              partial, E, N, chunk, (long)E, 0L);
    reduce2_kernel<<<rgrid, 256, 0, stream>>>(partial, values, err, dx,
                                              N, Kused);
}